// Round 8
// baseline (278.407 us; speedup 1.0000x reference)
//
#include <hip/hip_runtime.h>

// Problem dims
#define LL 1024
#define BB 8
#define EE 1024
#define HH 16
#define HD 64
#define MROWS (LL*BB)   // 8192 token rows

typedef __attribute__((ext_vector_type(8))) short short8v;   // 8 bf16 (4 VGPRs)
typedef __attribute__((ext_vector_type(4))) float f32x4;
typedef __attribute__((ext_vector_type(16))) float f32x16;

#define LOG2E 1.44269504088896f

__device__ __forceinline__ unsigned short tobf(float f) {
    union { float f; unsigned u; } un; un.f = f;
    unsigned u = un.u;
    u += 0x7fffu + ((u >> 16) & 1u);   // round-to-nearest-even
    return (unsigned short)(u >> 16);
}

__device__ __forceinline__ float max3f(float a, float b, float c) {
    return fmaxf(fmaxf(a, b), c);      // clang fuses to v_max3_f32
}

__device__ __forceinline__ void load_lds16(const unsigned short* g, unsigned short* l) {
    // async global->LDS, 16B per lane; LDS dest = wave-uniform base + lane*16
    __builtin_amdgcn_global_load_lds((const __attribute__((address_space(1))) unsigned int*)g,
                                     (__attribute__((address_space(3))) unsigned int*)l,
                                     16, 0, 0);
}

// ---------------- weight f32 -> bf16, 4 weights in one launch -----------------
__global__ __launch_bounds__(256) void convw4_kernel(const float* __restrict__ w0,
                                                     const float* __restrict__ w1,
                                                     const float* __restrict__ w2,
                                                     const float* __restrict__ w3,
                                                     unsigned short* __restrict__ o0,
                                                     unsigned short* __restrict__ o1,
                                                     unsigned short* __restrict__ o2,
                                                     unsigned short* __restrict__ o3) {
    const float* w; unsigned short* o;
    switch (blockIdx.y) {
        case 0:  w = w0; o = o0; break;
        case 1:  w = w1; o = o1; break;
        case 2:  w = w2; o = o2; break;
        default: w = w3; o = o3; break;
    }
    int i = (blockIdx.x * 256 + threadIdx.x) * 4;
    float4 v = *(const float4*)&w[i];
    ushort4 r;
    r.x = tobf(v.x); r.y = tobf(v.y); r.z = tobf(v.z); r.w = tobf(v.w);
    *(ushort4*)&o[i] = r;
}

// ---------------- mask prep: maskT2[k2][q] = pack(bf16(mask[q][2k2]*log2e),
//                  bf16(mask[q][2k2+1]*log2e)) — transposed, pair-packed -------
__global__ __launch_bounds__(256) void maskprep_kernel(const float* __restrict__ m,
                                                       unsigned* __restrict__ o) {
    __shared__ float t_sh[64][65];
    const int q0 = blockIdx.x * 64, k0 = blockIdx.y * 64;
    const int tid = threadIdx.x;
    {
        const int r = tid >> 2, c0 = (tid & 3) * 16;
        #pragma unroll
        for (int i = 0; i < 4; ++i) {
            float4 v = *(const float4*)&m[(size_t)(q0 + r) * LL + k0 + c0 + i*4];
            t_sh[r][c0+i*4+0] = v.x; t_sh[r][c0+i*4+1] = v.y;
            t_sh[r][c0+i*4+2] = v.z; t_sh[r][c0+i*4+3] = v.w;
        }
    }
    __syncthreads();
    const int k2l = tid >> 3, qi = (tid & 7) * 8;
    unsigned pk[8];
    #pragma unroll
    for (int j = 0; j < 8; ++j) {
        const unsigned lo = tobf(t_sh[qi+j][2*k2l]   * LOG2E);
        const unsigned hb = tobf(t_sh[qi+j][2*k2l+1] * LOG2E);
        pk[j] = lo | (hb << 16);
    }
    unsigned* orow = &o[(size_t)(k0/2 + k2l) * LL + q0 + qi];
    *(uint4*)&orow[0] = make_uint4(pk[0], pk[1], pk[2], pk[3]);
    *(uint4*)&orow[4] = make_uint4(pk[4], pk[5], pk[6], pk[7]);
}

// ---------------- LayerNorm: one block per token row, E=1024, 256 thr ---------
__global__ __launch_bounds__(256) void ln_kernel(const float* __restrict__ x,
                                                 const float* __restrict__ gamma,
                                                 const float* __restrict__ beta,
                                                 unsigned short* __restrict__ out) {
    const int row = blockIdx.x;
    const int tid = threadIdx.x;
    const float4 v = *(const float4*)&x[(size_t)row * EE + tid * 4];
    float s = v.x + v.y + v.z + v.w;
    float q = v.x*v.x + v.y*v.y + v.z*v.z + v.w*v.w;
    #pragma unroll
    for (int off = 1; off < 64; off <<= 1) {
        s += __shfl_xor(s, off);
        q += __shfl_xor(q, off);
    }
    __shared__ float ss[4], sq[4];
    const int wv = tid >> 6;
    if ((tid & 63) == 0) { ss[wv] = s; sq[wv] = q; }
    __syncthreads();
    s = ss[0] + ss[1] + ss[2] + ss[3];
    q = sq[0] + sq[1] + sq[2] + sq[3];
    const float mu = s * (1.0f / EE);
    const float var = q * (1.0f / EE) - mu * mu;
    const float rs = rsqrtf(var + 1e-5f);
    ushort4 o;
    o.x = tobf((v.x - mu) * rs * gamma[tid*4+0] + beta[tid*4+0]);
    o.y = tobf((v.y - mu) * rs * gamma[tid*4+1] + beta[tid*4+1]);
    o.z = tobf((v.z - mu) * rs * gamma[tid*4+2] + beta[tid*4+2]);
    o.w = tobf((v.w - mu) * rs * gamma[tid*4+3] + beta[tid*4+3]);
    *(ushort4*)&out[(size_t)row * EE + tid * 4] = o;
}

// ---------------- gemm_qkv: 256x256 tile, 8-phase-style schedule --------------
// C = A(8192 x 1024) @ W^T (W = [Wq;Wk;Wv], 3072 x 1024), all bf16 row-major.
// 512 thr = 8 waves (2M x 4N); per-wave output 128x64 (8x4 frags 16x16x32).
// K-tiles of 32; 3 LDS buffers; stage distance 2 tiles; boundary sync =
// s_waitcnt vmcnt(4) (counted, T4) + s_barrier. Two phases per K-tile, each
// {stage half-tile || ds_read frags -> barrier -> lgkmcnt(0)+sched_barrier ->
//  setprio(1) 16 MFMA setprio(0) -> barrier}  (T3 interleave, T5).
// LDS rows 64B (32 bf16); T2 swizzle: 16B-slot ^= (row&3), applied on BOTH the
// pre-swizzled gload source and the ds_read address (rule #21 involution).
__global__ __launch_bounds__(512, 2) void gemm_qkv256(const unsigned short* __restrict__ A,
                                                      const unsigned short* __restrict__ W,
                                                      const float* __restrict__ bq,
                                                      const float* __restrict__ bkb,
                                                      const float* __restrict__ bvb,
                                                      unsigned short* __restrict__ qo,
                                                      unsigned short* __restrict__ ko,
                                                      unsigned short* __restrict__ vo) {
    __shared__ __attribute__((aligned(16))) unsigned short a_sh[3][256*32];  // 48 KB
    __shared__ __attribute__((aligned(16))) unsigned short b_sh[3][256*32];  // 48 KB
    const int tid = threadIdx.x, lane = tid & 63, wave = tid >> 6;
    const int wm = wave >> 2, wn = wave & 3;
    const int l16 = lane & 15, q4 = lane >> 4;
    // XCD-chunked block mapping: 384 blocks = 8 chunks x (12 bx x 4 by), by-inner
    const int v   = (blockIdx.x & 7) * 48 + (blockIdx.x >> 3);
    const int by  = (v / 48) * 4 + (v & 3);
    const int bx  = (v % 48) >> 2;
    const int bm  = by * 256, bn = bx * 256;
    // stage lane geometry: 1KB window = 16 rows x 64B; lane -> row l>>2, slot l&3
    const int srow  = lane >> 2;
    const int sslot = ((lane & 3) ^ (srow & 3)) * 8;   // pre-swizzled source k-off
    const int rdsl  = (l16 & 3);                        // row&3 for ds_read swizzle

    auto stageA = [&](int d, int t) {
        #pragma unroll
        for (int i = 0; i < 2; ++i) {
            const int win = wave * 2 + i;  // 16-row window 0..15
            load_lds16(&A[(size_t)(bm + win*16 + srow) * EE + t*32 + sslot],
                       &a_sh[d][win * 512]);
        }
    };
    auto stageB = [&](int d, int t) {
        #pragma unroll
        for (int i = 0; i < 2; ++i) {
            const int win = wave * 2 + i;
            load_lds16(&W[(size_t)(bn + win*16 + srow) * EE + t*32 + sslot],
                       &b_sh[d][win * 512]);
        }
    };

    f32x4 acc[8][4] = {};
    stageA(0, 0); stageB(0, 0);
    stageA(1, 1); stageB(1, 1);

    int bufc = 0;
    for (int t = 0; t < 32; ++t) {
        if (t < 31) asm volatile("s_waitcnt vmcnt(4)" ::: "memory");
        else        asm volatile("s_waitcnt vmcnt(0)" ::: "memory");
        __builtin_amdgcn_s_barrier();
        const int sbuf = (bufc + 2 >= 3) ? bufc - 1 : bufc + 2;
        // ---- phase 0: stage A(t+2) || read B-frags + A-frags 0..3, MFMA ----
        if (t + 2 < 32) stageA(sbuf, t + 2);
        short8v bf[4], af[4];
        #pragma unroll
        for (int ni = 0; ni < 4; ++ni) {
            const int rB = wn*64 + ni*16 + l16;
            bf[ni] = *(const short8v*)((const char*)&b_sh[bufc][0]
                        + (size_t)rB*64 + ((q4 ^ rdsl) * 16));
        }
        #pragma unroll
        for (int mi = 0; mi < 4; ++mi) {
            const int rA = wm*128 + mi*16 + l16;
            af[mi] = *(const short8v*)((const char*)&a_sh[bufc][0]
                        + (size_t)rA*64 + ((q4 ^ rdsl) * 16));
        }
        __builtin_amdgcn_s_barrier();
        asm volatile("s_waitcnt lgkmcnt(0)" ::: "memory");
        __builtin_amdgcn_sched_barrier(0);
        __builtin_amdgcn_s_setprio(1);
        #pragma unroll
        for (int mi = 0; mi < 4; ++mi)
            #pragma unroll
            for (int ni = 0; ni < 4; ++ni)
                acc[mi][ni] = __builtin_amdgcn_mfma_f32_16x16x32_bf16(af[mi], bf[ni], acc[mi][ni], 0, 0, 0);
        __builtin_amdgcn_s_setprio(0);
        __builtin_amdgcn_s_barrier();
        // ---- phase 1: stage B(t+2) || read A-frags 4..7, MFMA ----
        if (t + 2 < 32) stageB(sbuf, t + 2);
        #pragma unroll
        for (int mi = 0; mi < 4; ++mi) {
            const int rA = wm*128 + (mi + 4)*16 + l16;
            af[mi] = *(const short8v*)((const char*)&a_sh[bufc][0]
                        + (size_t)rA*64 + ((q4 ^ rdsl) * 16));
        }
        __builtin_amdgcn_s_barrier();
        asm volatile("s_waitcnt lgkmcnt(0)" ::: "memory");
        __builtin_amdgcn_sched_barrier(0);
        __builtin_amdgcn_s_setprio(1);
        #pragma unroll
        for (int mi = 0; mi < 4; ++mi)
            #pragma unroll
            for (int ni = 0; ni < 4; ++ni)
                acc[mi + 4][ni] = __builtin_amdgcn_mfma_f32_16x16x32_bf16(af[mi], bf[ni], acc[mi + 4][ni], 0, 0, 0);
        __builtin_amdgcn_s_setprio(0);
        __builtin_amdgcn_s_barrier();
        bufc = (bufc + 1 == 3) ? 0 : bufc + 1;
    }
    // ---- epilogue: bias + scatter (seg uniform per block since BN=256 | 1024) --
    const int seg = bn >> 10;
    const float* bias = seg == 0 ? bq : (seg == 1 ? bkb : bvb);
    #pragma unroll
    for (int mi = 0; mi < 8; ++mi) {
        #pragma unroll
        for (int ni = 0; ni < 4; ++ni) {
            #pragma unroll
            for (int r = 0; r < 4; ++r) {
                const int m  = bm + wm*128 + mi*16 + q4*4 + r;
                const int nn = (bn & 1023) + wn*64 + ni*16 + l16;
                const float vv = acc[mi][ni][r] + bias[nn];
                const int l = m >> 3, b = m & 7, h = nn >> 6, d = nn & 63;
                if (seg == 0)      qo[((size_t)(b*HH + h) * LL + l) * HD + d] = tobf(vv * (0.125f * LOG2E));
                else if (seg == 1) ko[((size_t)(b*HH + h) * LL + l) * HD + d] = tobf(vv);
                else               vo[((size_t)(b*HH + h) * HD + d) * LL + l] = tobf(vv); // V^T
            }
        }
    }
}

// ---------------- 128x128-tile GEMM, BK=32, 3-buffer counted-vmcnt pipeline ---
// (kept for gemm_o only)
#define GEMM128_BODY(A_, W_)                                                              \
    __shared__ unsigned short a_sh[3][128*32];                                            \
    __shared__ unsigned short b_sh[3][128*32];                                            \
    const int tid = threadIdx.x, lane = tid & 63, wave = tid >> 6;                        \
    const int bm = blockIdx.y * 128, bn = blockIdx.x * 128;                               \
    const int wr = (wave >> 1) * 64, wc = (wave & 1) * 64;                                \
    const int l16 = lane & 15, q4 = lane >> 4;                                            \
    const int grow = lane >> 2;                                                           \
    const int gswz = (((lane & 3) ^ (grow & 3)) * 8);                                     \
    const int rslot = (q4 ^ (l16 & 3)) * 16;  /* ds_read byte slot */                     \
    f32x4 acc[4][4] = {};                                                                 \
    _Pragma("unroll")                                                                     \
    for (int i = 0; i < 2; ++i) {                                                         \
        const int ch = wave * 2 + i;                                                      \
        load_lds16(&A_[(size_t)(bm + ch*16 + grow)*EE + gswz], &a_sh[0][ch*512]);         \
        load_lds16(&W_[(size_t)(bn + ch*16 + grow)*EE + gswz], &b_sh[0][ch*512]);         \
    }                                                                                     \
    _Pragma("unroll")                                                                     \
    for (int i = 0; i < 2; ++i) {                                                         \
        const int ch = wave * 2 + i;                                                      \
        load_lds16(&A_[(size_t)(bm + ch*16 + grow)*EE + 32 + gswz], &a_sh[1][ch*512]);    \
        load_lds16(&W_[(size_t)(bn + ch*16 + grow)*EE + 32 + gswz], &b_sh[1][ch*512]);    \
    }                                                                                     \
    int buf = 0, sb = 2;                                                                  \
    for (int it = 0; it < 32; ++it) {                                                     \
        if (it < 31) asm volatile("s_waitcnt vmcnt(4)" ::: "memory");                     \
        else         asm volatile("s_waitcnt vmcnt(0)" ::: "memory");                     \
        __builtin_amdgcn_s_barrier();                                                     \
        if (it < 30) {                                                                    \
            const int kn = (it + 2) * 32;                                                 \
            _Pragma("unroll")                                                             \
            for (int i = 0; i < 2; ++i) {                                                 \
                const int ch = wave * 2 + i;                                              \
                load_lds16(&A_[(size_t)(bm + ch*16 + grow)*EE + kn + gswz], &a_sh[sb][ch*512]); \
                load_lds16(&W_[(size_t)(bn + ch*16 + grow)*EE + kn + gswz], &b_sh[sb][ch*512]); \
            }                                                                             \
        }                                                                                 \
        short8v af[4], bf[4];                                                             \
        _Pragma("unroll")                                                                 \
        for (int mi = 0; mi < 4; ++mi)                                                    \
            af[mi] = *(const short8v*)((const char*)&a_sh[buf][0] + (size_t)(wr + mi*16 + l16)*64 + rslot); \
        _Pragma("unroll")                                                                 \
        for (int ni = 0; ni < 4; ++ni)                                                    \
            bf[ni] = *(const short8v*)((const char*)&b_sh[buf][0] + (size_t)(wc + ni*16 + l16)*64 + rslot); \
        __builtin_amdgcn_s_setprio(1);                                                    \
        _Pragma("unroll")                                                                 \
        for (int mi = 0; mi < 4; ++mi)                                                    \
            _Pragma("unroll")                                                             \
            for (int ni = 0; ni < 4; ++ni)                                                \
                acc[mi][ni] = __builtin_amdgcn_mfma_f32_16x16x32_bf16(af[mi], bf[ni], acc[mi][ni], 0, 0, 0); \
        __builtin_amdgcn_s_setprio(0);                                                    \
        buf = (buf == 2) ? 0 : buf + 1;                                                   \
        sb  = (sb  == 2) ? 0 : sb  + 1;                                                   \
    }

// Output projection + bias + residual, f32 out.
__global__ __launch_bounds__(256) void gemm_o(const unsigned short* __restrict__ A,
                                              const unsigned short* __restrict__ W,
                                              const float* __restrict__ bias,
                                              const float* __restrict__ xres,
                                              float* __restrict__ outf) {
    GEMM128_BODY(A, W)
    #pragma unroll
    for (int mi = 0; mi < 4; ++mi) {
        #pragma unroll
        for (int ni = 0; ni < 4; ++ni) {
            #pragma unroll
            for (int r = 0; r < 4; ++r) {
                const int m = bm + wr + mi*16 + (lane >> 4)*4 + r;
                const int n = bn + wc + ni*16 + l16;
                outf[(size_t)m * EE + n] = acc[mi][ni][r] + bias[n] + xres[(size_t)m * EE + n];
            }
        }
    }
}

// ---------------- Flash attention, m214 structure + 3-buf counted pipeline ---
// (unchanged from round 7)
__global__ __launch_bounds__(256) void attn_kernel(const unsigned short* __restrict__ qarr,
                                                   const unsigned short* __restrict__ karr,
                                                   const unsigned short* __restrict__ vtarr,
                                                   const unsigned* __restrict__ maskT2,
                                                   unsigned short* __restrict__ attn_out) {
    __shared__ __attribute__((aligned(16))) unsigned short k_sh[3][64*64];  // [kv64][d64]
    __shared__ __attribute__((aligned(16))) unsigned short v_sh[3][64*64];  // [d64][kv64]
    const int tid = threadIdx.x, lane = tid & 63, wave = tid >> 6;
    const int l32 = lane & 31, hi = lane >> 5;
    const int bh = blockIdx.y;
    const int qtok = blockIdx.x * 128 + wave * 32 + l32;
    const unsigned short* qb = qarr  + (size_t)bh * LL * HD;
    const unsigned short* kb = karr  + (size_t)bh * LL * HD;
    const unsigned short* vb = vtarr + (size_t)bh * HD * LL;

    short8v qf[4];
    #pragma unroll
    for (int dc = 0; dc < 4; ++dc)
        qf[dc] = *(const short8v*)&qb[(size_t)qtok * HD + dc*16 + hi*8];

    f32x16 acc[2] = {};
    float mrun = -1e30f, srun = 0.f;

    auto stage = [&](int bufi, int kv) {
        #pragma unroll
        for (int i = 0; i < 2; ++i) {
            const int r = wave*16 + i*8 + (lane >> 3);
            const int c = ((lane & 7) ^ (r & 7)) * 8;
            load_lds16(&kb[(size_t)(kv + r) * HD + c], &k_sh[bufi][(wave*16 + i*8) * 64]);
            load_lds16(&vb[(size_t)r * LL + kv + c],   &v_sh[bufi][(wave*16 + i*8) * 64]);
        }
    };

    auto finish = [&](f32x16& s, const unsigned* mu, int sub, int bufi) {
        #pragma unroll
        for (int j = 0; j < 8; ++j) {
            s[2*j]   += __uint_as_float(mu[j] << 16);
            s[2*j+1] += __uint_as_float(mu[j] & 0xffff0000u);
        }
        const float a0 = max3f(s[0],  s[1],  s[2]);
        const float a1 = max3f(s[3],  s[4],  s[5]);
        const float a2 = max3f(s[6],  s[7],  s[8]);
        const float a3 = max3f(s[9],  s[10], s[11]);
        const float a4 = max3f(s[12], s[13], s[14]);
        float pm = fmaxf(max3f(a0, a1, a2), max3f(a3, a4, s[15]));
        pm = fmaxf(pm, __shfl_xor(pm, 32));
        if (__any(pm - mrun > 8.0f)) {
            const float mn = fmaxf(mrun, pm);
            const float al = exp2f(mrun - mn);
            #pragma unroll
            for (int i = 0; i < 16; ++i) { acc[0][i] *= al; acc[1][i] *= al; }
            srun *= al;
            mrun = mn;
        }
        float p[16];
        #pragma unroll
        for (int i = 0; i < 16; ++i) p[i] = exp2f(s[i] - mrun);
        const float t0 = p[0]+p[1],   t1 = p[2]+p[3],   t2 = p[4]+p[5],   t3 = p[6]+p[7];
        const float t4 = p[8]+p[9],   t5 = p[10]+p[11], t6 = p[12]+p[13], t7 = p[14]+p[15];
        const float u0 = t0+t1, u1 = t2+t3, u2 = t4+t5, u3 = t6+t7;
        float rs = (u0+u1) + (u2+u3);
        rs += __shfl_xor(rs, 32);
        srun += rs;
        unsigned w[8];
        #pragma unroll
        for (int j = 0; j < 8; ++j)
            asm("v_cvt_pk_bf16_f32 %0, %1, %2" : "=v"(w[j]) : "v"(p[2*j]), "v"(p[2*j+1]));
        asm volatile("v_permlane32_swap_b32 %0, %1" : "+v"(w[0]), "+v"(w[2]));
        asm volatile("v_permlane32_swap_b32 %0, %1" : "+v"(w[1]), "+v"(w[3]));
        asm volatile("v_permlane32_swap_b32 %0, %1" : "+v"(w[4]), "+v"(w[6]));
        asm volatile("v_permlane32_swap_b32 %0, %1" : "+v"(w[5]), "+v"(w[7]));
        union { uint4 u; short8v s8; } pb0, pb1;
        pb0.u = make_uint4(w[0], w[1], w[2], w[3]);
        pb1.u = make_uint4(w[4], w[5], w[6], w[7]);
        __builtin_amdgcn_s_setprio(1);
        #pragma unroll
        for (int dt = 0; dt < 2; ++dt) {
            const int row = dt*32 + l32;
            const short8v vf0 = *(const short8v*)((const char*)&v_sh[bufi][0]
                                  + (size_t)row*128 + ((((sub*2+0)*2 + hi) ^ (l32 & 7)) * 16));
            const short8v vf1 = *(const short8v*)((const char*)&v_sh[bufi][0]
                                  + (size_t)row*128 + ((((sub*2+1)*2 + hi) ^ (l32 & 7)) * 16));
            acc[dt] = __builtin_amdgcn_mfma_f32_32x32x16_bf16(vf0, pb0.s8, acc[dt], 0, 0, 0);
            acc[dt] = __builtin_amdgcn_mfma_f32_32x32x16_bf16(vf1, pb1.s8, acc[dt], 0, 0, 0);
        }
        __builtin_amdgcn_s_setprio(0);
    };

    const unsigned* mt2base = maskT2 + qtok;
    stage(0, 0);
    unsigned mcur[16], mnxt[16];
    #pragma unroll
    for (int j = 0; j < 8; ++j) {
        mcur[j]     = mt2base[(size_t)((j & 1) + 4*(j >> 1) + 2*hi) * LL];
        mcur[8 + j] = mt2base[(size_t)(16 + (j & 1) + 4*(j >> 1) + 2*hi) * LL];
    }
    stage(1, 64);

    const int NT = LL / 64;
    int buf = 0, sb = 2;
    for (int t = 0; t < NT; ++t) {
        if (t < NT - 1) asm volatile("s_waitcnt vmcnt(4)" ::: "memory");
        else            asm volatile("s_waitcnt vmcnt(0)" ::: "memory");
        __builtin_amdgcn_s_barrier();
        if (t < NT - 1) {
            const unsigned* mt2n = mt2base + (size_t)(t + 1) * 32 * LL;
            #pragma unroll
            for (int j = 0; j < 8; ++j) {
                mnxt[j]     = mt2n[(size_t)((j & 1) + 4*(j >> 1) + 2*hi) * LL];
                mnxt[8 + j] = mt2n[(size_t)(16 + (j & 1) + 4*(j >> 1) + 2*hi) * LL];
            }
        }
        if (t + 2 < NT) stage(sb, (t + 2) * 64);

        f32x16 s0 = {}, s1 = {};
        __builtin_amdgcn_s_setprio(1);
        #pragma unroll
        for (int dc = 0; dc < 4; ++dc) {
            const short8v kf = *(const short8v*)((const char*)&k_sh[buf][0]
                                 + (size_t)(l32)*128 + (((dc*2 + hi) ^ (l32 & 7)) * 16));
            s0 = __builtin_amdgcn_mfma_f32_32x32x16_bf16(kf, qf[dc], s0, 0, 0, 0);
        }
        #pragma unroll
        for (int dc = 0; dc < 4; ++dc) {
            const short8v kf = *(const short8v*)((const char*)&k_sh[buf][0]
                                 + (size_t)(32 + l32)*128 + (((dc*2 + hi) ^ (l32 & 7)) * 16));
            s1 = __builtin_amdgcn_mfma_f32_32x32x16_bf16(kf, qf[dc], s1, 0, 0, 0);
        }
        __builtin_amdgcn_s_setprio(0);
        finish(s0, &mcur[0], 0, buf);
        finish(s1, &mcur[8], 1, buf);
        #pragma unroll
        for (int j = 0; j < 16; ++j) mcur[j] = mnxt[j];
        buf = (buf == 2) ? 0 : buf + 1;
        sb  = (sb  == 2) ? 0 : sb  + 1;
    }
    const float inv = 1.0f / srun;
    const int b = bh >> 4, h = bh & 15;
    unsigned short* orow = attn_out + ((size_t)qtok * BB + b) * EE + h * HD;
    #pragma unroll
    for (int dt = 0; dt < 2; ++dt) {
        #pragma unroll
        for (int g = 0; g < 4; ++g) {
            const float a0 = acc[dt][4*g+0]*inv, a1 = acc[dt][4*g+1]*inv;
            const float a2 = acc[dt][4*g+2]*inv, a3 = acc[dt][4*g+3]*inv;
            unsigned lo, hw;
            asm("v_cvt_pk_bf16_f32 %0, %1, %2" : "=v"(lo) : "v"(a0), "v"(a1));
            asm("v_cvt_pk_bf16_f32 %0, %1, %2" : "=v"(hw) : "v"(a2), "v"(a3));
            *(uint2*)&orow[dt*32 + g*8 + hi*4] = make_uint2(lo, hw);
        }
    }
}

extern "C" void kernel_launch(void* const* d_in, const int* in_sizes, int n_in,
                              void* d_out, int out_size, void* d_ws, size_t ws_size,
                              hipStream_t stream) {
    (void)in_sizes; (void)n_in; (void)out_size; (void)ws_size;
    const float* x     = (const float*)d_in[0];
    const float* mask  = (const float*)d_in[1];
    const float* Wq    = (const float*)d_in[2];
    const float* bq    = (const float*)d_in[3];
    const float* Wk    = (const float*)d_in[4];
    const float* bk    = (const float*)d_in[5];
    const float* Wv    = (const float*)d_in[6];
    const float* bv    = (const float*)d_in[7];
    const float* Wo    = (const float*)d_in[8];
    const float* bo    = (const float*)d_in[9];
    const float* gamma = (const float*)d_in[10];
    const float* beta  = (const float*)d_in[11];
    float* out = (float*)d_out;

    // workspace layout (ushort units); total exactly 72 MiB — no growth allowed
    unsigned short* ws   = (unsigned short*)d_ws;
    unsigned short* ln   = ws;                          // 8192*1024 (reused as attnb)
    unsigned short* wqkv = ln   + (size_t)MROWS * EE;   // 3 x 1024 x 1024 (Wq;Wk;Wv)
    unsigned short* wob  = wqkv + (size_t)3 * EE * EE;
    unsigned short* qb   = wob  + (size_t)EE * EE;      // (B,H,L,HD)
    unsigned short* kbp  = qb   + (size_t)BB * HH * LL * HD;
    unsigned short* vtb  = kbp  + (size_t)BB * HH * LL * HD;  // (B,H,HD,L)
    unsigned short* attnb = ln;                         // reuse after QKV GEMM
    unsigned* maskT2 = (unsigned*)wqkv;                 // reuse wqkv AFTER gemm_qkv

    convw4_kernel<<<dim3(1024, 4), 256, 0, stream>>>(
        Wq, Wk, Wv, Wo,
        wqkv, wqkv + (size_t)EE * EE, wqkv + (size_t)2 * EE * EE, wob);
    ln_kernel<<<MROWS, 256, 0, stream>>>(x, gamma, beta, ln);

    gemm_qkv256<<<384, 512, 0, stream>>>(ln, wqkv, bq, bk, bv, qb, kbp, vtb);

    // wqkv now dead -> build transposed pair-packed mask in its space
    maskprep_kernel<<<dim3(16, 16), 256, 0, stream>>>(mask, maskT2);

    attn_kernel<<<dim3(LL / 128, BB * HH), 256, 0, stream>>>(qb, kbp, vtb, maskT2, attnb);

    gemm_o<<<dim3(8, 64), 256, 0, stream>>>(attnb, wob, bo, x, out);
}

// Round 9
// 223.280 us; speedup vs baseline: 1.2469x; 1.2469x over previous
//
#include <hip/hip_runtime.h>

// Problem dims
#define LL 1024
#define BB 8
#define EE 1024
#define HH 16
#define HD 64
#define MROWS (LL*BB)   // 8192 token rows

typedef __attribute__((ext_vector_type(8))) short short8v;   // 8 bf16 (4 VGPRs)
typedef __attribute__((ext_vector_type(4))) float f32x4;
typedef __attribute__((ext_vector_type(16))) float f32x16;

#define LOG2E 1.44269504088896f

__device__ __forceinline__ unsigned short tobf(float f) {
    union { float f; unsigned u; } un; un.f = f;
    unsigned u = un.u;
    u += 0x7fffu + ((u >> 16) & 1u);   // round-to-nearest-even
    return (unsigned short)(u >> 16);
}

__device__ __forceinline__ float max3f(float a, float b, float c) {
    return fmaxf(fmaxf(a, b), c);      // clang fuses to v_max3_f32
}

__device__ __forceinline__ void load_lds16(const unsigned short* g, unsigned short* l) {
    // async global->LDS, 16B per lane; LDS dest = wave-uniform base + lane*16
    __builtin_amdgcn_global_load_lds((const __attribute__((address_space(1))) unsigned int*)g,
                                     (__attribute__((address_space(3))) unsigned int*)l,
                                     16, 0, 0);
}

// ---------------- weight f32 -> bf16, 4 weights in one launch -----------------
__global__ __launch_bounds__(256) void convw4_kernel(const float* __restrict__ w0,
                                                     const float* __restrict__ w1,
                                                     const float* __restrict__ w2,
                                                     const float* __restrict__ w3,
                                                     unsigned short* __restrict__ o0,
                                                     unsigned short* __restrict__ o1,
                                                     unsigned short* __restrict__ o2,
                                                     unsigned short* __restrict__ o3) {
    const float* w; unsigned short* o;
    switch (blockIdx.y) {
        case 0:  w = w0; o = o0; break;
        case 1:  w = w1; o = o1; break;
        case 2:  w = w2; o = o2; break;
        default: w = w3; o = o3; break;
    }
    int i = (blockIdx.x * 256 + threadIdx.x) * 4;
    float4 v = *(const float4*)&w[i];
    ushort4 r;
    r.x = tobf(v.x); r.y = tobf(v.y); r.z = tobf(v.z); r.w = tobf(v.w);
    *(ushort4*)&o[i] = r;
}

// ---------------- mask prep: maskT2[k2][q] = pack(bf16(mask[q][2k2]*log2e),
//                  bf16(mask[q][2k2+1]*log2e)) — transposed, pair-packed -------
__global__ __launch_bounds__(256) void maskprep_kernel(const float* __restrict__ m,
                                                       unsigned* __restrict__ o) {
    __shared__ float t_sh[64][65];
    const int q0 = blockIdx.x * 64, k0 = blockIdx.y * 64;
    const int tid = threadIdx.x;
    {
        const int r = tid >> 2, c0 = (tid & 3) * 16;
        #pragma unroll
        for (int i = 0; i < 4; ++i) {
            float4 v = *(const float4*)&m[(size_t)(q0 + r) * LL + k0 + c0 + i*4];
            t_sh[r][c0+i*4+0] = v.x; t_sh[r][c0+i*4+1] = v.y;
            t_sh[r][c0+i*4+2] = v.z; t_sh[r][c0+i*4+3] = v.w;
        }
    }
    __syncthreads();
    const int k2l = tid >> 3, qi = (tid & 7) * 8;
    unsigned pk[8];
    #pragma unroll
    for (int j = 0; j < 8; ++j) {
        const unsigned lo = tobf(t_sh[qi+j][2*k2l]   * LOG2E);
        const unsigned hb = tobf(t_sh[qi+j][2*k2l+1] * LOG2E);
        pk[j] = lo | (hb << 16);
    }
    unsigned* orow = &o[(size_t)(k0/2 + k2l) * LL + q0 + qi];
    *(uint4*)&orow[0] = make_uint4(pk[0], pk[1], pk[2], pk[3]);
    *(uint4*)&orow[4] = make_uint4(pk[4], pk[5], pk[6], pk[7]);
}

// ---------------- LayerNorm: one block per token row, E=1024, 256 thr ---------
__global__ __launch_bounds__(256) void ln_kernel(const float* __restrict__ x,
                                                 const float* __restrict__ gamma,
                                                 const float* __restrict__ beta,
                                                 unsigned short* __restrict__ out) {
    const int row = blockIdx.x;
    const int tid = threadIdx.x;
    const float4 v = *(const float4*)&x[(size_t)row * EE + tid * 4];
    float s = v.x + v.y + v.z + v.w;
    float q = v.x*v.x + v.y*v.y + v.z*v.z + v.w*v.w;
    #pragma unroll
    for (int off = 1; off < 64; off <<= 1) {
        s += __shfl_xor(s, off);
        q += __shfl_xor(q, off);
    }
    __shared__ float ss[4], sq[4];
    const int wv = tid >> 6;
    if ((tid & 63) == 0) { ss[wv] = s; sq[wv] = q; }
    __syncthreads();
    s = ss[0] + ss[1] + ss[2] + ss[3];
    q = sq[0] + sq[1] + sq[2] + sq[3];
    const float mu = s * (1.0f / EE);
    const float var = q * (1.0f / EE) - mu * mu;
    const float rs = rsqrtf(var + 1e-5f);
    ushort4 o;
    o.x = tobf((v.x - mu) * rs * gamma[tid*4+0] + beta[tid*4+0]);
    o.y = tobf((v.y - mu) * rs * gamma[tid*4+1] + beta[tid*4+1]);
    o.z = tobf((v.z - mu) * rs * gamma[tid*4+2] + beta[tid*4+2]);
    o.w = tobf((v.w - mu) * rs * gamma[tid*4+3] + beta[tid*4+3]);
    *(ushort4*)&out[(size_t)row * EE + tid * 4] = o;
}

// ---------------- 128x128-tile GEMM, BK=32, 3-buffer counted-vmcnt pipeline ---
#define GEMM128_BODY(A_, W_)                                                              \
    __shared__ unsigned short a_sh[3][128*32];                                            \
    __shared__ unsigned short b_sh[3][128*32];                                            \
    const int tid = threadIdx.x, lane = tid & 63, wave = tid >> 6;                        \
    const int bm = blockIdx.y * 128, bn = blockIdx.x * 128;                               \
    const int wr = (wave >> 1) * 64, wc = (wave & 1) * 64;                                \
    const int l16 = lane & 15, q4 = lane >> 4;                                            \
    const int grow = lane >> 2;                                                           \
    const int gswz = (((lane & 3) ^ (grow & 3)) * 8);                                     \
    const int rslot = (q4 ^ (l16 & 3)) * 16;  /* ds_read byte slot */                     \
    f32x4 acc[4][4] = {};                                                                 \
    _Pragma("unroll")                                                                     \
    for (int i = 0; i < 2; ++i) {                                                         \
        const int ch = wave * 2 + i;                                                      \
        load_lds16(&A_[(size_t)(bm + ch*16 + grow)*EE + gswz], &a_sh[0][ch*512]);         \
        load_lds16(&W_[(size_t)(bn + ch*16 + grow)*EE + gswz], &b_sh[0][ch*512]);         \
    }                                                                                     \
    _Pragma("unroll")                                                                     \
    for (int i = 0; i < 2; ++i) {                                                         \
        const int ch = wave * 2 + i;                                                      \
        load_lds16(&A_[(size_t)(bm + ch*16 + grow)*EE + 32 + gswz], &a_sh[1][ch*512]);    \
        load_lds16(&W_[(size_t)(bn + ch*16 + grow)*EE + 32 + gswz], &b_sh[1][ch*512]);    \
    }                                                                                     \
    int buf = 0, sb = 2;                                                                  \
    for (int it = 0; it < 32; ++it) {                                                     \
        if (it < 31) asm volatile("s_waitcnt vmcnt(4)" ::: "memory");                     \
        else         asm volatile("s_waitcnt vmcnt(0)" ::: "memory");                     \
        __builtin_amdgcn_s_barrier();                                                     \
        if (it < 30) {                                                                    \
            const int kn = (it + 2) * 32;                                                 \
            _Pragma("unroll")                                                             \
            for (int i = 0; i < 2; ++i) {                                                 \
                const int ch = wave * 2 + i;                                              \
                load_lds16(&A_[(size_t)(bm + ch*16 + grow)*EE + kn + gswz], &a_sh[sb][ch*512]); \
                load_lds16(&W_[(size_t)(bn + ch*16 + grow)*EE + kn + gswz], &b_sh[sb][ch*512]); \
            }                                                                             \
        }                                                                                 \
        short8v af[4], bf[4];                                                             \
        _Pragma("unroll")                                                                 \
        for (int mi = 0; mi < 4; ++mi)                                                    \
            af[mi] = *(const short8v*)((const char*)&a_sh[buf][0] + (size_t)(wr + mi*16 + l16)*64 + rslot); \
        _Pragma("unroll")                                                                 \
        for (int ni = 0; ni < 4; ++ni)                                                    \
            bf[ni] = *(const short8v*)((const char*)&b_sh[buf][0] + (size_t)(wc + ni*16 + l16)*64 + rslot); \
        __builtin_amdgcn_s_setprio(1);                                                    \
        _Pragma("unroll")                                                                 \
        for (int mi = 0; mi < 4; ++mi)                                                    \
            _Pragma("unroll")                                                             \
            for (int ni = 0; ni < 4; ++ni)                                                \
                acc[mi][ni] = __builtin_amdgcn_mfma_f32_16x16x32_bf16(af[mi], bf[ni], acc[mi][ni], 0, 0, 0); \
        __builtin_amdgcn_s_setprio(0);                                                    \
        buf = (buf == 2) ? 0 : buf + 1;                                                   \
        sb  = (sb  == 2) ? 0 : sb  + 1;                                                   \
    }

// QKV fused: W = [Wq;Wk;Wv] (3072 x 1024). Segment uniform per block.
// Epilogue scatters Q/K/V into MFMA-FRAGMENT layouts consumed LDS-free by attn:
//   Q_frag/K_frag: [bh][t32][dc][lane][8], lane=hi*32+l32 <-> (token=t32*32+l32,
//                  d=dc*16+hi*8+e)     (B-operand of mfma_32x32x16: col=token)
//   V_frag:        [bh][k16][dt][lane][8], lane=khi*32+dl  <-> (key=k16*16+khi*8+ke,
//                  d=dt*32+dl)         (A-operand rows = d)
__global__ __launch_bounds__(256) void gemm_qkv(const unsigned short* __restrict__ A,
                                                const unsigned short* __restrict__ W,
                                                const float* __restrict__ bq,
                                                const float* __restrict__ bk,
                                                const float* __restrict__ bv,
                                                unsigned short* __restrict__ qo,
                                                unsigned short* __restrict__ ko,
                                                unsigned short* __restrict__ vo) {
    GEMM128_BODY(A, W)
    const int seg = blockIdx.x >> 3;
    const float* bias = seg == 0 ? bq : (seg == 1 ? bk : bv);
    #pragma unroll
    for (int mi = 0; mi < 4; ++mi) {
        #pragma unroll
        for (int ni = 0; ni < 4; ++ni) {
            #pragma unroll
            for (int r = 0; r < 4; ++r) {
                const int m  = bm + wr + mi*16 + (lane >> 4)*4 + r;
                const int nn = (bn & 1023) + wc + ni*16 + l16;
                const float v = acc[mi][ni][r] + bias[nn];
                const int l = m >> 3, b = m & 7, h = nn >> 6, d = nn & 63;
                const int bh = b*HH + h;
                if (seg == 2) {
                    // V fragment layout
                    const int k16 = l >> 4, khi = (l >> 3) & 1, ke = l & 7;
                    const int dt = d >> 5, dl = d & 31;
                    vo[((((size_t)bh*64 + k16)*2 + dt)*64 + khi*32 + dl)*8 + ke] = tobf(v);
                } else {
                    // Q/K fragment layout (identical index form)
                    const int t32 = l >> 5, l32 = l & 31;
                    const int dc = d >> 4, hi2 = (d >> 3) & 1, e = d & 7;
                    const size_t idx = ((((size_t)bh*32 + t32)*4 + dc)*64 + hi2*32 + l32)*8 + e;
                    if (seg == 0) qo[idx] = tobf(v * (0.125f * LOG2E));  // exp2-domain Q
                    else          ko[idx] = tobf(v);
                }
            }
        }
    }
}

// Output projection + bias + residual, f32 out.
__global__ __launch_bounds__(256) void gemm_o(const unsigned short* __restrict__ A,
                                              const unsigned short* __restrict__ W,
                                              const float* __restrict__ bias,
                                              const float* __restrict__ xres,
                                              float* __restrict__ outf) {
    GEMM128_BODY(A, W)
    #pragma unroll
    for (int mi = 0; mi < 4; ++mi) {
        #pragma unroll
        for (int ni = 0; ni < 4; ++ni) {
            #pragma unroll
            for (int r = 0; r < 4; ++r) {
                const int m = bm + wr + mi*16 + (lane >> 4)*4 + r;
                const int n = bn + wc + ni*16 + l16;
                outf[(size_t)m * EE + n] = acc[mi][ni][r] + bias[n] + xres[(size_t)m * EE + n];
            }
        }
    }
}

// ---------------- Flash attention: LDS-free, fragment-layout operands --------
// K+V per (b,h) = 256 KB -> L2-resident (Common-mistake #7 / m169: skip LDS
// staging when data cache-fits). All operand loads are coalesced dwordx4 from
// frag-layout buffers; waves fully independent (no barriers, no vmcnt games).
// 1-D grid XCD-swizzled so all 8 blocks of one (b,h) share an XCD's L2.
// Per 32-key tile: 4 K-frag loads -> 4 QK MFMA -> {V-frag + next-K + mask
// prefetch under softmax} -> 4 PV MFMA. Softmax in-register (exp2 domain).
__global__ __launch_bounds__(256) void attn_kernel(const unsigned short* __restrict__ Qf,
                                                   const unsigned short* __restrict__ Kf,
                                                   const unsigned short* __restrict__ Vf,
                                                   const unsigned* __restrict__ maskT2,
                                                   unsigned short* __restrict__ attn_out) {
    const int tid = threadIdx.x, lane = tid & 63, wave = tid >> 6;
    const int l32 = lane & 31, hi = lane >> 5;
    const int b1 = blockIdx.x;
    const int bh = (b1 & 7) * 16 + ((b1 >> 3) & 15);   // all 8 blocks of bh -> same XCD
    const int qt = ((b1 >> 7) & 7) * 4 + wave;          // 32-token q tile
    const int qtok = qt * 32 + l32;
    const unsigned short* qfp = Qf + ((size_t)(bh * 32 + qt) * 4) * 512;
    const unsigned short* kfb = Kf + (size_t)bh * 32 * 4 * 512;
    const unsigned short* vfb = Vf + (size_t)bh * 64 * 2 * 512;

    short8v qf[4];
    #pragma unroll
    for (int dc = 0; dc < 4; ++dc)
        qf[dc] = *(const short8v*)&qfp[dc * 512 + lane * 8];

    f32x16 acc[2] = {};           // O^T accumulator: dt=0 (d 0..31), dt=1 (d 32..63)
    float mrun = -1e30f, srun = 0.f;

    const unsigned* mt2base = maskT2 + qtok;
    short8v kf[4];
    #pragma unroll
    for (int dc = 0; dc < 4; ++dc)
        kf[dc] = *(const short8v*)&kfb[dc * 512 + lane * 8];
    unsigned mcur[8], mnxt[8];
    #pragma unroll
    for (int j = 0; j < 8; ++j)
        mcur[j] = mt2base[(size_t)((j & 1) + 4*(j >> 1) + 2*hi) * LL];

    for (int t = 0; t < 32; ++t) {
        // ---- S^T = K . Q^T over d=64 (4 chained mfma) ----
        f32x16 s = {};
        __builtin_amdgcn_s_setprio(1);
        #pragma unroll
        for (int dc = 0; dc < 4; ++dc)
            s = __builtin_amdgcn_mfma_f32_32x32x16_bf16(kf[dc], qf[dc], s, 0, 0, 0);
        __builtin_amdgcn_s_setprio(0);
        // ---- prefetch: this tile's V frags, next tile's K frags + mask ----
        short8v vf00, vf01, vf10, vf11;   // [ks][dt]
        vf00 = *(const short8v*)&vfb[((size_t)(t*2 + 0)*2 + 0)*512 + lane*8];
        vf01 = *(const short8v*)&vfb[((size_t)(t*2 + 0)*2 + 1)*512 + lane*8];
        vf10 = *(const short8v*)&vfb[((size_t)(t*2 + 1)*2 + 0)*512 + lane*8];
        vf11 = *(const short8v*)&vfb[((size_t)(t*2 + 1)*2 + 1)*512 + lane*8];
        if (t < 31) {
            #pragma unroll
            for (int dc = 0; dc < 4; ++dc)
                kf[dc] = *(const short8v*)&kfb[((size_t)(t + 1)*4 + dc)*512 + lane*8];
            #pragma unroll
            for (int j = 0; j < 8; ++j)
                mnxt[j] = mt2base[(size_t)((t + 1)*16 + (j & 1) + 4*(j >> 1) + 2*hi) * LL];
        }
        // ---- softmax finish (exp2 domain; mask pre-scaled by log2e) ----
        #pragma unroll
        for (int j = 0; j < 8; ++j) {
            s[2*j]   += __uint_as_float(mcur[j] << 16);
            s[2*j+1] += __uint_as_float(mcur[j] & 0xffff0000u);
        }
        const float a0 = max3f(s[0],  s[1],  s[2]);
        const float a1 = max3f(s[3],  s[4],  s[5]);
        const float a2 = max3f(s[6],  s[7],  s[8]);
        const float a3 = max3f(s[9],  s[10], s[11]);
        const float a4 = max3f(s[12], s[13], s[14]);
        float pm = fmaxf(max3f(a0, a1, a2), max3f(a3, a4, s[15]));
        pm = fmaxf(pm, __shfl_xor(pm, 32));
        if (__any(pm - mrun > 8.0f)) {     // T13 defer-max rescale
            const float mn = fmaxf(mrun, pm);
            const float al = exp2f(mrun - mn);
            #pragma unroll
            for (int i = 0; i < 16; ++i) { acc[0][i] *= al; acc[1][i] *= al; }
            srun *= al;
            mrun = mn;
        }
        float p[16];
        #pragma unroll
        for (int i = 0; i < 16; ++i) p[i] = exp2f(s[i] - mrun);
        const float t0 = p[0]+p[1],   t1 = p[2]+p[3],   t2 = p[4]+p[5],   t3 = p[6]+p[7];
        const float t4 = p[8]+p[9],   t5 = p[10]+p[11], t6 = p[12]+p[13], t7 = p[14]+p[15];
        const float u0 = t0+t1, u1 = t2+t3, u2 = t4+t5, u3 = t6+t7;
        float rs = (u0+u1) + (u2+u3);
        rs += __shfl_xor(rs, 32);
        srun += rs;
        // ---- P -> bf16 B-frags via cvt_pk + permlane32_swap (T12) ----
        unsigned w[8];
        #pragma unroll
        for (int j = 0; j < 8; ++j)
            asm("v_cvt_pk_bf16_f32 %0, %1, %2" : "=v"(w[j]) : "v"(p[2*j]), "v"(p[2*j+1]));
        asm volatile("v_permlane32_swap_b32 %0, %1" : "+v"(w[0]), "+v"(w[2]));
        asm volatile("v_permlane32_swap_b32 %0, %1" : "+v"(w[1]), "+v"(w[3]));
        asm volatile("v_permlane32_swap_b32 %0, %1" : "+v"(w[4]), "+v"(w[6]));
        asm volatile("v_permlane32_swap_b32 %0, %1" : "+v"(w[5]), "+v"(w[7]));
        union { uint4 u; short8v s8; } pb0, pb1;
        pb0.u = make_uint4(w[0], w[1], w[2], w[3]);   // k-chain 0..15
        pb1.u = make_uint4(w[4], w[5], w[6], w[7]);   // k-chain 16..31
        // ---- O^T += V^T . P  (4 mfma) ----
        __builtin_amdgcn_s_setprio(1);
        acc[0] = __builtin_amdgcn_mfma_f32_32x32x16_bf16(vf00, pb0.s8, acc[0], 0, 0, 0);
        acc[1] = __builtin_amdgcn_mfma_f32_32x32x16_bf16(vf01, pb0.s8, acc[1], 0, 0, 0);
        acc[0] = __builtin_amdgcn_mfma_f32_32x32x16_bf16(vf10, pb1.s8, acc[0], 0, 0, 0);
        acc[1] = __builtin_amdgcn_mfma_f32_32x32x16_bf16(vf11, pb1.s8, acc[1], 0, 0, 0);
        __builtin_amdgcn_s_setprio(0);
        #pragma unroll
        for (int j = 0; j < 8; ++j) mcur[j] = mnxt[j];
    }
    // ---- epilogue: O = acc/srun, packed 8B stores ----
    const float inv = 1.0f / srun;
    const int b = bh >> 4, h = bh & 15;
    unsigned short* orow = attn_out + ((size_t)qtok * BB + b) * EE + h * HD;
    #pragma unroll
    for (int dt = 0; dt < 2; ++dt) {
        #pragma unroll
        for (int g = 0; g < 4; ++g) {
            const float a0 = acc[dt][4*g+0]*inv, a1 = acc[dt][4*g+1]*inv;
            const float a2 = acc[dt][4*g+2]*inv, a3 = acc[dt][4*g+3]*inv;
            unsigned lo, hw;
            asm("v_cvt_pk_bf16_f32 %0, %1, %2" : "=v"(lo) : "v"(a0), "v"(a1));
            asm("v_cvt_pk_bf16_f32 %0, %1, %2" : "=v"(hw) : "v"(a2), "v"(a3));
            *(uint2*)&orow[dt*32 + g*8 + hi*4] = make_uint2(lo, hw);
        }
    }
}

extern "C" void kernel_launch(void* const* d_in, const int* in_sizes, int n_in,
                              void* d_out, int out_size, void* d_ws, size_t ws_size,
                              hipStream_t stream) {
    (void)in_sizes; (void)n_in; (void)out_size; (void)ws_size;
    const float* x     = (const float*)d_in[0];
    const float* mask  = (const float*)d_in[1];
    const float* Wq    = (const float*)d_in[2];
    const float* bq    = (const float*)d_in[3];
    const float* Wk    = (const float*)d_in[4];
    const float* bk    = (const float*)d_in[5];
    const float* Wv    = (const float*)d_in[6];
    const float* bv    = (const float*)d_in[7];
    const float* Wo    = (const float*)d_in[8];
    const float* bo    = (const float*)d_in[9];
    const float* gamma = (const float*)d_in[10];
    const float* beta  = (const float*)d_in[11];
    float* out = (float*)d_out;

    // workspace layout (ushort units); total exactly 72 MiB — no growth allowed
    unsigned short* ws   = (unsigned short*)d_ws;
    unsigned short* ln   = ws;                          // 8192*1024 (reused as attnb)
    unsigned short* wqkv = ln   + (size_t)MROWS * EE;   // 3 x 1024 x 1024 (Wq;Wk;Wv)
    unsigned short* wob  = wqkv + (size_t)3 * EE * EE;
    unsigned short* qb   = wob  + (size_t)EE * EE;      // Q fragments
    unsigned short* kbp  = qb   + (size_t)BB * HH * LL * HD;  // K fragments
    unsigned short* vtb  = kbp  + (size_t)BB * HH * LL * HD;  // V fragments
    unsigned short* attnb = ln;                         // reuse after QKV GEMM
    unsigned* maskT2 = (unsigned*)wqkv;                 // reuse wqkv AFTER gemm_qkv

    convw4_kernel<<<dim3(1024, 4), 256, 0, stream>>>(
        Wq, Wk, Wv, Wo,
        wqkv, wqkv + (size_t)EE * EE, wqkv + (size_t)2 * EE * EE, wob);
    ln_kernel<<<MROWS, 256, 0, stream>>>(x, gamma, beta, ln);

    gemm_qkv<<<dim3(24, 64), 256, 0, stream>>>(ln, wqkv, bq, bk, bv, qb, kbp, vtb);

    // wqkv now dead -> build transposed pair-packed mask in its space
    maskprep_kernel<<<dim3(16, 16), 256, 0, stream>>>(mask, maskT2);

    attn_kernel<<<1024, 256, 0, stream>>>(qb, kbp, vtb, maskT2, attnb);

    gemm_o<<<dim3(8, 64), 256, 0, stream>>>(attnb, wob, bo, x, out);
}